// Round 13
// baseline (29727.283 us; speedup 1.0000x reference)
//
#include <hip/hip_runtime.h>
#include <cmath>

// HM-LSTM forward, MI355X. Round 13: ROW-PARTITIONED chains (no global sync).
// Key insight (missed for 12 rounds): the recurrence is INDEPENDENT PER BATCH
// ROW. Only weights are shared. So: 8 groups x 8 rows, each group = 8 WGs
// (column shards). Sync domain = 8 WGs on a group-private atomic line
// (r8-proven RMW+poll primitives; no 256-agent convoy). Weights stacked
// [k][col] and XCD-sharded via blockIdx%8 -> each XCD L2 caches ~1MB shard.
// h state lives directly in d_out (sc1 stores, unique-write-then-read reads:
// the r8-proven visibility pattern); z in padded ws entries (fp64, s>0).
// Normal launch (64 blocks always co-resident), watchdog on the spin.

#define Hh    256
#define Bb    64
#define Tt    512
#define GC    1025
#define NGRP  8
#define RPG   8          // rows per group
#define NSH   8          // shards per group (WGs)
#define APAD  12         // A_lds row stride (floats): bank-safe + 16B aligned
#define WDOG  400000

__device__ __forceinline__ void g_st(float* p, float v) {
    __hip_atomic_store(p, v, __ATOMIC_RELAXED, __HIP_MEMORY_SCOPE_AGENT);
}
__device__ __forceinline__ unsigned int a_add(unsigned int* p, unsigned int v) {
    return __hip_atomic_fetch_add(p, v, __ATOMIC_RELAXED, __HIP_MEMORY_SCOPE_AGENT);
}
__device__ __forceinline__ unsigned int a_ld32(const unsigned int* p) {
    return __hip_atomic_load(p, __ATOMIC_RELAXED, __HIP_MEMORY_SCOPE_AGENT);
}

// ---------------------------------------------------------------------------
// Prep: build stacked weights Wstk_l[k][1025] (rows: bottom(256);recur(256);
// top(256, l<2)) + compact z-columns wz[l][k].
// ---------------------------------------------------------------------------
struct WSrc { const float* wb[3]; const float* wr[3]; const float* wt[3]; };

__global__ __launch_bounds__(256) void build_wstk(WSrc S, float* __restrict__ wstk,
                                                  float* __restrict__ wz) {
    const int gk = blockIdx.x;           // 0..2047
    int l, k;
    if (gk < 768)       { l = 0; k = gk; }
    else if (gk < 1536) { l = 1; k = gk - 768; }
    else                { l = 2; k = gk - 1536; }   // 512 rows
    const float* src;
    if (k < 256)      src = S.wb[l] + (size_t)k * GC;
    else if (k < 512) src = S.wr[l] + (size_t)(k - 256) * GC;
    else              src = S.wt[l] + (size_t)(k - 512) * GC;
    float* dst = wstk + (size_t)l * 768 * GC + (size_t)k * GC;
#pragma unroll
    for (int i = 0; i < 5; ++i) {
        int c = i * 256 + threadIdx.x;
        if (c < GC) {
            float v = src[c];
            dst[c] = v;
            if (c == 1024) wz[l * 768 + k] = v;
        }
    }
}

// ---------------------------------------------------------------------------
// Main persistent chain kernel. Grid 64 x 512. blockIdx = group*8 + shard
// is NOT used (we want blockIdx%8 == shard for XCD locality):
// shard = blockIdx%8, group = blockIdx/8.
// ---------------------------------------------------------------------------
struct PK {
    const float* x;         // (64,512,256)
    const float* wstk;      // stacked weights
    const float* wz;        // [3][768] z columns
    const float* bias[3];   // (1025,)
    float* zws;             // z state: ((row*1539)+(t*3+l))*32
    unsigned int* bar;      // NGRP lines, 32 uints apart
    float* out_h;           // (64,512,768) — doubles as h state
    float* out_z;           // (64,512,3)
};

__global__ __launch_bounds__(512, 1) void chain_kernel(PK P) {
    __shared__ float A[768 * APAD];          // [k][row] gated inputs, 36.9KB
    __shared__ float red[NSH][128][8];       // [wave][col_local][row], 32KB
    __shared__ float zbS[8], zoS[8];

    const int tid   = threadIdx.x;
    const int lane  = tid & 63;
    const int wave  = tid >> 6;              // 0..7
    const int shard = blockIdx.x & 7;
    const int group = blockIdx.x >> 3;
    const int row0  = group * RPG;

    unsigned int* grpCnt = P.bar + group * 32;
    unsigned int stage = 0;
    bool broken = false;

    // per-thread cell state: thread tid<256 owns (row=tid>>5, j=tid&31)
    float creg[3] = {0.f, 0.f, 0.f};
    float hreg[3] = {0.f, 0.f, 0.f};

    // GEMV lane columns: col_local = lane (gi 0/1) and 64+lane (gi 2/3)
    const int gi0 = lane >> 5;               // 0 or 1
    const int jl  = lane & 31;
    const size_t cA = (size_t)(gi0 * 256 + shard * 32 + jl);
    const size_t cB = (size_t)((gi0 + 2) * 256 + shard * 32 + jl);

    for (int t = 0; t < Tt; ++t) {
#pragma unroll
        for (int l = 0; l < 3; ++l) {
            const int K = (l < 2) ? 768 : 512;
            const float* __restrict__ Wl = P.wstk + (size_t)l * 768 * GC;
            const float* __restrict__ bias = P.bias[l];

            // ---- 1. per-row gate scalars ----
            if (tid < 8) {
                const int r = row0 + tid;
                float zo = (t > 0) ? P.zws[((size_t)r * 1539 + ((t - 1) * 3 + l)) * 32] : 0.f;
                float zb = (l == 0) ? 1.f
                         : P.zws[((size_t)r * 1539 + (t * 3 + l - 1)) * 32];
                zoS[tid] = zo; zbS[tid] = zb;
            }
            __syncthreads();

            // ---- 2. stage gated inputs A[k][row] ----
            for (int e = tid; e < RPG * K; e += 512) {
                const int row = e / K;
                const int k   = e - row * K;
                const int r   = row0 + row;
                float v;
                if (k < 256) {
                    float b = (l == 0)
                        ? P.x[((size_t)r * Tt + t) * 256 + k]
                        : P.out_h[((size_t)r * Tt + t) * 768 + (l - 1) * 256 + k];
                    v = zbS[row] * b;
                } else if (k < 512) {
                    v = (t > 0)
                        ? P.out_h[((size_t)r * Tt + (t - 1)) * 768 + l * 256 + (k - 256)]
                        : 0.f;
                } else {
                    float tp = (t > 0)
                        ? P.out_h[((size_t)r * Tt + (t - 1)) * 768 + (l + 1) * 256 + (k - 512)]
                        : 0.f;
                    v = zoS[row] * tp;
                }
                A[k * APAD + row] = v;
            }
            __syncthreads();

            // ---- 3. GEMV: wave = K-chunk; lane = 2 cols; 8 rows ----
            {
                const int Klen = K >> 3;
                const int k0   = wave * Klen;
                float acc0[8], acc1[8];
#pragma unroll
                for (int r = 0; r < 8; ++r) { acc0[r] = 0.f; acc1[r] = 0.f; }
                for (int k = k0; k < k0 + Klen; ++k) {
                    const float4* ap = (const float4*)&A[k * APAD];
                    float4 a03 = ap[0];
                    float4 a47 = ap[1];
                    const float* wrow = Wl + (size_t)k * GC;
                    float w0 = wrow[cA];
                    float w1 = wrow[cB];
                    acc0[0] += w0 * a03.x; acc0[1] += w0 * a03.y;
                    acc0[2] += w0 * a03.z; acc0[3] += w0 * a03.w;
                    acc0[4] += w0 * a47.x; acc0[5] += w0 * a47.y;
                    acc0[6] += w0 * a47.z; acc0[7] += w0 * a47.w;
                    acc1[0] += w1 * a03.x; acc1[1] += w1 * a03.y;
                    acc1[2] += w1 * a03.z; acc1[3] += w1 * a03.w;
                    acc1[4] += w1 * a47.x; acc1[5] += w1 * a47.y;
                    acc1[6] += w1 * a47.z; acc1[7] += w1 * a47.w;
                }
                const int cl0 = gi0 * 32 + jl;         // col_local of cA
                const int cl1 = (gi0 + 2) * 32 + jl;   // col_local of cB
#pragma unroll
                for (int r = 0; r < 8; ++r) red[wave][cl0][r] = acc0[r];
#pragma unroll
                for (int r = 0; r < 8; ++r) red[wave][cl1][r] = acc1[r];
            }

            // ---- 4. z column (shard 7): fp64, wave=row, lane=k strided ----
            float znew_wave = 0.f;
            if (shard == 7) {
                const float* __restrict__ wzl = P.wz + l * 768;
                double zp = 0.0;
                for (int k = lane; k < K; k += 64)
                    zp += (double)wzl[k] * (double)A[k * APAD + wave];
#pragma unroll
                for (int off = 32; off > 0; off >>= 1)
                    zp += __shfl_down(zp, off);
                if (lane == 0) {
                    double s = (double)bias[1024] + zp;
                    // round(clip((s+1)/2,0,1)) round-half-even == (s > 0)
                    znew_wave = (s > 0.0) ? 1.0f : 0.0f;
                    const int r = row0 + wave;
                    g_st(&P.zws[((size_t)r * 1539 + (t * 3 + l)) * 32], znew_wave);
                    P.out_z[((size_t)r * Tt + t) * 3 + l] = znew_wave;
                }
            }
            __syncthreads();

            // ---- 5. epilogue: threads 0..255 own (row, j) ----
            if (tid < 256) {
                const int row = tid >> 5;
                const int j   = tid & 31;
                const int r   = row0 + row;
                float s0 = bias[0 * Hh + shard * 32 + j];
                float s1 = bias[1 * Hh + shard * 32 + j];
                float s2 = bias[2 * Hh + shard * 32 + j];
                float s3 = bias[3 * Hh + shard * 32 + j];
#pragma unroll
                for (int w = 0; w < 8; ++w) {
                    s0 += red[w][0 * 32 + j][row];
                    s1 += red[w][1 * 32 + j][row];
                    s2 += red[w][2 * 32 + j][row];
                    s3 += red[w][3 * 32 + j][row];
                }
                float f = 1.0f / (1.0f + expf(-s0));
                float i = 1.0f / (1.0f + expf(-s1));
                float o = 1.0f / (1.0f + expf(-s2));
                float g = tanhf(s3);
                float zb_ = zbS[row];
                float zo_ = zoS[row];
                float c    = creg[l];
                float hold = hreg[l];
                float ig   = i * g;
                float cupd = f * c + ig;
                // z,zb in {0,1} exactly -> selects == reference arithmetic
                float cnew = (zo_ != 0.0f) ? ig : ((zb_ != 0.0f) ? cupd : c);
                float hnew = (zo_ == 0.0f && zb_ == 0.0f) ? hold : (o * tanhf(cnew));
                creg[l] = cnew;
                hreg[l] = hnew;
                g_st(&P.out_h[((size_t)r * Tt + t) * 768 + l * 256 + shard * 32 + j], hnew);
            }

            // ---- 6. 8-agent group barrier (r8-proven RMW + poll) ----
            __syncthreads();   // drains vmcnt: h/z sc1 stores L3-visible
            if (tid == 0) {
                a_add(grpCnt, 1u);
                if (!broken) {
                    const unsigned int tgt = 8u * (stage + 1u);
                    unsigned int v = 0; int it = 0;
                    for (; it < WDOG; ++it) {
                        v = a_ld32(grpCnt);
                        if (v >= tgt) break;
                        __builtin_amdgcn_s_sleep(2);
                    }
                    broken = (v < tgt);
                }
            }
            __syncthreads();
            ++stage;
        }
    }
}

extern "C" void kernel_launch(void* const* d_in, const int* in_sizes, int n_in,
                              void* d_out, int out_size, void* d_ws, size_t ws_size,
                              hipStream_t stream) {
    (void)in_sizes; (void)n_in; (void)out_size;

    // dict order: x, Wb0,Wr0,Wt0,b0, Wb1,Wr1,Wt1,b1, Wb2,Wr2,Wt2,b2
    const float* x = (const float*)d_in[0];
    float* wsf = (float*)d_ws;

    // ws layout (floats)
    const size_t OFF_WSTK = 0;                         // 3*768*1025 (l2 uses 512)
    const size_t OFF_WZ   = OFF_WSTK + (size_t)3 * 768 * GC;   // 2,359,575 -> pad
    const size_t OFF_ZWS  = OFF_WZ + 3 * 768 + 64;
    const size_t OFF_BAR  = OFF_ZWS + (size_t)64 * 1539 * 32;  // +3,151,872
    const size_t OFF_END  = OFF_BAR + 1024;

    float* wstk = wsf + OFF_WSTK;
    float* wz   = wsf + OFF_WZ;
    float* zws  = wsf + OFF_ZWS;
    unsigned int* bar = (unsigned int*)(wsf + OFF_BAR);

    if (ws_size < OFF_END * sizeof(float)) return;     // ~22MB; ws proven >=110MB

    // zero the barrier lines each call (graph-captured; zws is written-before-
    // read in-kernel and fully deterministic across replays).
    hipMemsetAsync(bar, 0, 1024 * sizeof(float), stream);

    WSrc S;
    S.wb[0] = (const float*)d_in[1];  S.wr[0] = (const float*)d_in[2];  S.wt[0] = (const float*)d_in[3];
    S.wb[1] = (const float*)d_in[5];  S.wr[1] = (const float*)d_in[6];  S.wt[1] = (const float*)d_in[7];
    S.wb[2] = (const float*)d_in[9];  S.wr[2] = (const float*)d_in[10]; S.wt[2] = (const float*)d_in[11];
    build_wstk<<<2048, 256, 0, stream>>>(S, wstk, wz);

    PK pk;
    pk.x = x;
    pk.wstk = wstk;
    pk.wz = wz;
    pk.bias[0] = (const float*)d_in[4];
    pk.bias[1] = (const float*)d_in[8];
    pk.bias[2] = (const float*)d_in[12];
    pk.zws = zws;
    pk.bar = bar;
    pk.out_h = (float*)d_out;
    pk.out_z = (float*)d_out + (size_t)Bb * Tt * 768;

    chain_kernel<<<64, 512, 0, stream>>>(pk);
}

// Round 14
// 18530.415 us; speedup vs baseline: 1.6042x; 1.6042x over previous
//
#include <hip/hip_runtime.h>
#include <cmath>

// HM-LSTM forward, MI355X. Round 14 = r13 chain design + two counter-driven fixes.
// r13 (passed, 29.7ms, 19.5us/stage): 8 groups x 8 rows, 8 column-shard WGs
// per group, 8-agent group barrier, weights XCD-sharded (FETCH=0.6GB proves
// L2-resident), h state in d_out via sc1 stores + unique-read, z in zws (fp64,
// s>0). Measured costs: 192 scalar weight loads/lane/stage (latency-bound,
// ~4-5us) and SQ_LDS_BANK_CONFLICT=2.6e8 (red[] 8-way).
// Fixes (structure otherwise byte-identical):
//  1. k4-blocked weights W4[l][k/4][col][4]: float4 load = 4 k's per issue,
//     coalesced across lanes -> 48 issues/lane (4x fewer), deeper MLP.
//  2. red[8][128][9] (stride-9): gather/scatter <=2-way instead of 8-way.

#define Hh    256
#define Bb    64
#define Tt    512
#define GC    1025
#define NGRP  8
#define RPG   8          // rows per group
#define NSH   8          // shards per group (WGs)
#define APAD  12         // A_lds row stride (floats): 16B-aligned f4 broadcast
#define WDOG  400000

__device__ __forceinline__ void g_st(float* p, float v) {
    __hip_atomic_store(p, v, __ATOMIC_RELAXED, __HIP_MEMORY_SCOPE_AGENT);
}
__device__ __forceinline__ unsigned int a_add(unsigned int* p, unsigned int v) {
    return __hip_atomic_fetch_add(p, v, __ATOMIC_RELAXED, __HIP_MEMORY_SCOPE_AGENT);
}
__device__ __forceinline__ unsigned int a_ld32(const unsigned int* p) {
    return __hip_atomic_load(p, __ATOMIC_RELAXED, __HIP_MEMORY_SCOPE_AGENT);
}

// ---------------------------------------------------------------------------
// Prep: pack weights k4-blocked: w4[((l*192 + k/4)*1024 + col)*4 + k%4]
// (cols 0..1023 = gates f,i,o,g), z column -> wz[l*768+k]. Row source per
// (l,k): k<256 bottom, k<512 recurrent, else top.
// ---------------------------------------------------------------------------
struct WSrc { const float* wb[3]; const float* wr[3]; const float* wt[3]; };

__global__ __launch_bounds__(256) void build_w4(WSrc S, float* __restrict__ w4,
                                                float* __restrict__ wz) {
    const int gk = blockIdx.x;           // 0..2047
    int l, k;
    if (gk < 768)       { l = 0; k = gk; }
    else if (gk < 1536) { l = 1; k = gk - 768; }
    else                { l = 2; k = gk - 1536; }   // 512 rows
    const float* src;
    if (k < 256)      src = S.wb[l] + (size_t)k * GC;
    else if (k < 512) src = S.wr[l] + (size_t)(k - 256) * GC;
    else              src = S.wt[l] + (size_t)(k - 512) * GC;
    float* dst = w4 + (((size_t)l * 192 + (k >> 2)) * 1024) * 4 + (k & 3);
#pragma unroll
    for (int i = 0; i < 5; ++i) {
        int c = i * 256 + threadIdx.x;
        if (c < 1024)      dst[(size_t)c * 4] = src[c];
        else if (c == 1024) wz[l * 768 + k] = src[c];
    }
}

// ---------------------------------------------------------------------------
// Main chain kernel. Grid 64 x 512. shard = blockIdx%8 (XCD locality),
// group = blockIdx/8. Each group owns 8 batch rows end-to-end.
// ---------------------------------------------------------------------------
struct PK {
    const float* x;         // (64,512,256)
    const float* w4;        // k4-packed weights
    const float* wz;        // [3][768] z columns
    const float* bias[3];   // (1025,)
    float* zws;             // z state: ((row*1539)+(t*3+l))*32
    unsigned int* bar;      // NGRP lines, 32 uints apart
    float* out_h;           // (64,512,768) — doubles as h state
    float* out_z;           // (64,512,3)
};

__global__ __launch_bounds__(512, 1) void chain_kernel(PK P) {
    __shared__ float A[768 * APAD];          // [k][row] gated inputs, 36.9KB
    __shared__ float red[NSH][128][9];       // [wave][col_local][row], 36.9KB
    __shared__ float zbS[8], zoS[8];

    const int tid   = threadIdx.x;
    const int lane  = tid & 63;
    const int wave  = tid >> 6;              // 0..7
    const int shard = blockIdx.x & 7;
    const int group = blockIdx.x >> 3;
    const int row0  = group * RPG;

    unsigned int* grpCnt = P.bar + group * 32;
    unsigned int stage = 0;
    bool broken = false;

    float creg[3] = {0.f, 0.f, 0.f};
    float hreg[3] = {0.f, 0.f, 0.f};

    // GEMV lane columns (within [0,1024)): gate blocks {gi0, gi0+2}
    const int gi0 = lane >> 5;               // 0 or 1
    const int jl  = lane & 31;
    const size_t cA = (size_t)(gi0 * 256 + shard * 32 + jl);
    const size_t cB = (size_t)((gi0 + 2) * 256 + shard * 32 + jl);

    for (int t = 0; t < Tt; ++t) {
#pragma unroll
        for (int l = 0; l < 3; ++l) {
            const int K = (l < 2) ? 768 : 512;
            const float* __restrict__ bias = P.bias[l];

            // ---- 1. per-row gate scalars ----
            if (tid < 8) {
                const int r = row0 + tid;
                float zo = (t > 0) ? P.zws[((size_t)r * 1539 + ((t - 1) * 3 + l)) * 32] : 0.f;
                float zb = (l == 0) ? 1.f
                         : P.zws[((size_t)r * 1539 + (t * 3 + l - 1)) * 32];
                zoS[tid] = zo; zbS[tid] = zb;
            }
            __syncthreads();

            // ---- 2. stage gated inputs A[k][row] ----
            for (int e = tid; e < RPG * K; e += 512) {
                const int row = e / K;
                const int k   = e - row * K;
                const int r   = row0 + row;
                float v;
                if (k < 256) {
                    float b = (l == 0)
                        ? P.x[((size_t)r * Tt + t) * 256 + k]
                        : P.out_h[((size_t)r * Tt + t) * 768 + (l - 1) * 256 + k];
                    v = zbS[row] * b;
                } else if (k < 512) {
                    v = (t > 0)
                        ? P.out_h[((size_t)r * Tt + (t - 1)) * 768 + l * 256 + (k - 256)]
                        : 0.f;
                } else {
                    float tp = (t > 0)
                        ? P.out_h[((size_t)r * Tt + (t - 1)) * 768 + (l + 1) * 256 + (k - 512)]
                        : 0.f;
                    v = zoS[row] * tp;
                }
                A[k * APAD + row] = v;
            }
            __syncthreads();

            // ---- 3. GEMV: wave = k4-block chunk; lane = 2 cols x 8 rows ----
            {
                const int Kb  = K >> 5;              // k4-blocks per wave (24 or 16)
                const int kb0 = wave * Kb;
                const float4* __restrict__ W4l =
                    (const float4*)P.w4 + (size_t)l * 192 * 1024;
                float acc0[8], acc1[8];
#pragma unroll
                for (int r = 0; r < 8; ++r) { acc0[r] = 0.f; acc1[r] = 0.f; }
                for (int kb = kb0; kb < kb0 + Kb; ++kb) {
                    float4 w0 = W4l[(size_t)kb * 1024 + cA];
                    float4 w1 = W4l[(size_t)kb * 1024 + cB];
#pragma unroll
                    for (int q = 0; q < 4; ++q) {
                        const float4* ap = (const float4*)&A[(kb * 4 + q) * APAD];
                        float4 a03 = ap[0];
                        float4 a47 = ap[1];
                        const float wq0 = (&w0.x)[q];
                        const float wq1 = (&w1.x)[q];
                        acc0[0] += wq0 * a03.x; acc0[1] += wq0 * a03.y;
                        acc0[2] += wq0 * a03.z; acc0[3] += wq0 * a03.w;
                        acc0[4] += wq0 * a47.x; acc0[5] += wq0 * a47.y;
                        acc0[6] += wq0 * a47.z; acc0[7] += wq0 * a47.w;
                        acc1[0] += wq1 * a03.x; acc1[1] += wq1 * a03.y;
                        acc1[2] += wq1 * a03.z; acc1[3] += wq1 * a03.w;
                        acc1[4] += wq1 * a47.x; acc1[5] += wq1 * a47.y;
                        acc1[6] += wq1 * a47.z; acc1[7] += wq1 * a47.w;
                    }
                }
                const int cl0 = gi0 * 32 + jl;         // col_local of cA
                const int cl1 = (gi0 + 2) * 32 + jl;   // col_local of cB
#pragma unroll
                for (int r = 0; r < 8; ++r) red[wave][cl0][r] = acc0[r];
#pragma unroll
                for (int r = 0; r < 8; ++r) red[wave][cl1][r] = acc1[r];
            }

            // ---- 4. z column (shard 7): fp64, wave=row, lane=k strided ----
            if (shard == 7) {
                const float* __restrict__ wzl = P.wz + l * 768;
                double zp = 0.0;
                for (int k = lane; k < K; k += 64)
                    zp += (double)wzl[k] * (double)A[k * APAD + wave];
#pragma unroll
                for (int off = 32; off > 0; off >>= 1)
                    zp += __shfl_down(zp, off);
                if (lane == 0) {
                    double s = (double)bias[1024] + zp;
                    // round(clip((s+1)/2,0,1)) round-half-even == (s > 0)
                    float znew = (s > 0.0) ? 1.0f : 0.0f;
                    const int r = row0 + wave;
                    g_st(&P.zws[((size_t)r * 1539 + (t * 3 + l)) * 32], znew);
                    P.out_z[((size_t)r * Tt + t) * 3 + l] = znew;
                }
            }
            __syncthreads();

            // ---- 5. epilogue: threads 0..255 own (row, j) ----
            if (tid < 256) {
                const int row = tid >> 5;
                const int j   = tid & 31;
                const int r   = row0 + row;
                float s0 = bias[0 * Hh + shard * 32 + j];
                float s1 = bias[1 * Hh + shard * 32 + j];
                float s2 = bias[2 * Hh + shard * 32 + j];
                float s3 = bias[3 * Hh + shard * 32 + j];
#pragma unroll
                for (int w = 0; w < 8; ++w) {
                    s0 += red[w][0 * 32 + j][row];
                    s1 += red[w][1 * 32 + j][row];
                    s2 += red[w][2 * 32 + j][row];
                    s3 += red[w][3 * 32 + j][row];
                }
                float f = 1.0f / (1.0f + expf(-s0));
                float i = 1.0f / (1.0f + expf(-s1));
                float o = 1.0f / (1.0f + expf(-s2));
                float g = tanhf(s3);
                float zb_ = zbS[row];
                float zo_ = zoS[row];
                float c    = creg[l];
                float hold = hreg[l];
                float ig   = i * g;
                float cupd = f * c + ig;
                // z,zb in {0,1} exactly -> selects == reference arithmetic
                float cnew = (zo_ != 0.0f) ? ig : ((zb_ != 0.0f) ? cupd : c);
                float hnew = (zo_ == 0.0f && zb_ == 0.0f) ? hold : (o * tanhf(cnew));
                creg[l] = cnew;
                hreg[l] = hnew;
                g_st(&P.out_h[((size_t)r * Tt + t) * 768 + l * 256 + shard * 32 + j], hnew);
            }

            // ---- 6. 8-agent group barrier (r13-proven RMW + poll) ----
            __syncthreads();   // drains vmcnt: h/z sc1 stores L3-visible
            if (tid == 0) {
                a_add(grpCnt, 1u);
                if (!broken) {
                    const unsigned int tgt = 8u * (stage + 1u);
                    unsigned int v = 0; int it = 0;
                    for (; it < WDOG; ++it) {
                        v = a_ld32(grpCnt);
                        if (v >= tgt) break;
                        __builtin_amdgcn_s_sleep(2);
                    }
                    broken = (v < tgt);
                }
            }
            __syncthreads();
            ++stage;
        }
    }
}

extern "C" void kernel_launch(void* const* d_in, const int* in_sizes, int n_in,
                              void* d_out, int out_size, void* d_ws, size_t ws_size,
                              hipStream_t stream) {
    (void)in_sizes; (void)n_in; (void)out_size;

    // dict order: x, Wb0,Wr0,Wt0,b0, Wb1,Wr1,Wt1,b1, Wb2,Wr2,Wt2,b2
    const float* x = (const float*)d_in[0];
    float* wsf = (float*)d_ws;

    // ws layout (floats)
    const size_t OFF_W4  = 0;                               // 3*192*1024*4
    const size_t OFF_WZ  = OFF_W4 + (size_t)3 * 192 * 1024 * 4;
    const size_t OFF_ZWS = OFF_WZ + 3 * 768 + 64;
    const size_t OFF_BAR = OFF_ZWS + (size_t)64 * 1539 * 32;
    const size_t OFF_END = OFF_BAR + 1024;

    float* w4  = wsf + OFF_W4;
    float* wz  = wsf + OFF_WZ;
    float* zws = wsf + OFF_ZWS;
    unsigned int* bar = (unsigned int*)(wsf + OFF_BAR);

    if (ws_size < OFF_END * sizeof(float)) return;     // ~22MB; ws proven >=110MB

    hipMemsetAsync(bar, 0, 1024 * sizeof(float), stream);

    WSrc S;
    S.wb[0] = (const float*)d_in[1];  S.wr[0] = (const float*)d_in[2];  S.wt[0] = (const float*)d_in[3];
    S.wb[1] = (const float*)d_in[5];  S.wr[1] = (const float*)d_in[6];  S.wt[1] = (const float*)d_in[7];
    S.wb[2] = (const float*)d_in[9];  S.wr[2] = (const float*)d_in[10]; S.wt[2] = (const float*)d_in[11];
    build_w4<<<2048, 256, 0, stream>>>(S, w4, wz);

    PK pk;
    pk.x = x;
    pk.w4 = w4;
    pk.wz = wz;
    pk.bias[0] = (const float*)d_in[4];
    pk.bias[1] = (const float*)d_in[8];
    pk.bias[2] = (const float*)d_in[12];
    pk.zws = zws;
    pk.bar = bar;
    pk.out_h = (float*)d_out;
    pk.out_z = (float*)d_out + (size_t)Bb * Tt * 768;

    chain_kernel<<<64, 512, 0, stream>>>(pk);
}